// Round 16
// baseline (412.891 us; speedup 1.0000x reference)
//
#include <hip/hip_runtime.h>
#include <hip/hip_bf16.h>

typedef __hip_bfloat16 bf16;
using f32x4  = __attribute__((ext_vector_type(4))) float;
using short8 = __attribute__((ext_vector_type(8))) short;

// B=8, T=12, N=325, K=8 heads, d=64, D=512, BT=96, M=31200 (padded 31232)
#define M_ROWS   31200
#define M_PAD    31232
#define N_TOK    325
#define D_MODEL  512
#define QKV_LD   1536

#define GLOBAL_AS(p) ((const __attribute__((address_space(1))) unsigned int*)(p))
#define LDS_AS(p)    ((__attribute__((address_space(3))) unsigned int*)(p))

// ---------------------------------------------------------------------------
// dtype detection: device inputs are either f32 or bf16 (flag=1 -> f32).
__global__ void init_flag(int* flag) { if (threadIdx.x == 0) *flag = 0; }

__global__ void detect_dtype(const unsigned short* __restrict__ x, int* flag)
{
    int i = blockIdx.x * 256 + threadIdx.x;   // 64 blocks * 256 = 16384 halves
    unsigned short h = x[i];
    int e = (h >> 7) & 0xFF;
    if (e >= 135) atomicOr(flag, 1);
}

__device__ __forceinline__ float load_in(const void* p, size_t i, bool f32)
{
    return f32 ? ((const float*)p)[i] : __bfloat162float(((const bf16*)p)[i]);
}

// ---------------------------------------------------------------------------
// tiled transpose: src [krows][ncols] -> dst [ncols][krows] bf16 (coalesced)
__global__ void transpose_w_tiled(const void* __restrict__ src, bf16* __restrict__ dst,
                                  int krows, int ncols, const int* __restrict__ flag)
{
    __shared__ float tile[32][33];
    const bool f32 = (*flag != 0);
    const int kt = blockIdx.y * 32, nt = blockIdx.x * 32;
    const int tx = threadIdx.x & 31, ty = threadIdx.x >> 5;   // 32 x 8
#pragma unroll
    for (int r = 0; r < 32; r += 8)
        tile[ty + r][tx] = load_in(src, (size_t)(kt + ty + r) * ncols + (nt + tx), f32);
    __syncthreads();
#pragma unroll
    for (int r = 0; r < 32; r += 8)
        dst[(size_t)(nt + ty + r) * krows + (kt + tx)] = __float2bfloat16(tile[tx][ty + r]);
}

__global__ void prep_bias(const void* __restrict__ bq, const void* __restrict__ bk,
                          const void* __restrict__ bv, const void* __restrict__ b1,
                          const void* __restrict__ b2,
                          float* __restrict__ biasQKV, float* __restrict__ b1f,
                          float* __restrict__ b2f, const int* __restrict__ flag)
{
    const bool f32 = (*flag != 0);
    int i = blockIdx.x * 256 + threadIdx.x;
    if (i < 512) {
        biasQKV[i]        = load_in(bq, i, f32);
        biasQKV[512 + i]  = load_in(bk, i, f32);
        biasQKV[1024 + i] = load_in(bv, i, f32);
        b1f[i] = load_in(b1, i, f32);
        b2f[i] = load_in(b2, i, f32);
    }
}

// ---------------------------------------------------------------------------
// Fused QKV GEMM: concat(X,STE) folded into A-staging. 256x128 tile, 512
// threads, BK=64. Since 512 % 64 == 0, each BK panel is entirely X or STE
// (wave-uniform base select per k-step). A reg-staged (f32->cvt or bf16
// passthrough) + ds_write_b128; B via global_load_lds (unchanged pattern).
__global__ __launch_bounds__(512) void gemm_qkv(
    const void* __restrict__ Xv, const void* __restrict__ STEv,
    const bf16* __restrict__ Bt, const float* __restrict__ bias,
    bf16* __restrict__ C, const int* __restrict__ flag)
{
    __shared__ alignas(16) bf16 As0[256 * 32];
    __shared__ alignas(16) bf16 As1[256 * 32];
    __shared__ alignas(16) bf16 Bs0[128 * 32];
    __shared__ alignas(16) bf16 Bs1[128 * 32];
    const bool f32 = (*flag != 0);
    const int cpx = gridDim.x >> 3;
    const int swz = (blockIdx.x & 7) * cpx + (blockIdx.x >> 3);
    const int m0 = (swz / 12) * 256;
    const int n0 = (swz % 12) * 128;
    const int t = threadIdx.x, wave = t >> 6, lane = t & 63;
    const int wm = (wave >> 1) * 64, wn = (wave & 1) * 64;
    const int lrow = lane & 15, lk8 = (lane >> 4) * 8;
    const int srow = lane >> 2, scol = (lane & 3) << 3;
    f32x4 acc[4][4] = {};

    for (int ks = 0; ks < 16; ++ks) {
        const int kk = ks << 6;
        const void* src = (kk < 512) ? Xv : STEv;   // whole BK panel one source
        const int kc = kk & 511;
        __syncthreads();   // previous tile's LDS reads complete
        // ---- A: reg-staged concat+cast (2 chunks x 16 rows)
#pragma unroll
        for (int c = 0; c < 2; ++c) {
            const int arow = wave * 32 + c * 16;
            const int grow = m0 + arow + srow;
            short8 va0 = {0,0,0,0,0,0,0,0}, va1 = {0,0,0,0,0,0,0,0};
            if (grow < M_ROWS) {
                if (f32) {
                    const float* s = (const float*)src + (size_t)grow * 512 + kc + scol;
                    float4 a0 = *(const float4*)(s);
                    float4 a1 = *(const float4*)(s + 4);
                    float4 b0 = *(const float4*)(s + 32);
                    float4 b1 = *(const float4*)(s + 36);
                    ((bf16*)&va0)[0] = __float2bfloat16(a0.x); ((bf16*)&va0)[1] = __float2bfloat16(a0.y);
                    ((bf16*)&va0)[2] = __float2bfloat16(a0.z); ((bf16*)&va0)[3] = __float2bfloat16(a0.w);
                    ((bf16*)&va0)[4] = __float2bfloat16(a1.x); ((bf16*)&va0)[5] = __float2bfloat16(a1.y);
                    ((bf16*)&va0)[6] = __float2bfloat16(a1.z); ((bf16*)&va0)[7] = __float2bfloat16(a1.w);
                    ((bf16*)&va1)[0] = __float2bfloat16(b0.x); ((bf16*)&va1)[1] = __float2bfloat16(b0.y);
                    ((bf16*)&va1)[2] = __float2bfloat16(b0.z); ((bf16*)&va1)[3] = __float2bfloat16(b0.w);
                    ((bf16*)&va1)[4] = __float2bfloat16(b1.x); ((bf16*)&va1)[5] = __float2bfloat16(b1.y);
                    ((bf16*)&va1)[6] = __float2bfloat16(b1.z); ((bf16*)&va1)[7] = __float2bfloat16(b1.w);
                } else {
                    const bf16* s = (const bf16*)src + (size_t)grow * 512 + kc + scol;
                    va0 = *(const short8*)(s);
                    va1 = *(const short8*)(s + 32);
                }
            }
            *(short8*)&As0[(arow + srow) * 32 + scol] = va0;
            *(short8*)&As1[(arow + srow) * 32 + scol] = va1;
        }
        // ---- B: global_load_lds (unchanged verified pattern)
        {
            const int brow = wave * 16;
            const bf16* gb = Bt + (size_t)(n0 + brow + srow) * 1024 + kk + scol;
            __builtin_amdgcn_global_load_lds(GLOBAL_AS(gb),      LDS_AS(Bs0 + brow * 32), 16, 0, 0);
            __builtin_amdgcn_global_load_lds(GLOBAL_AS(gb + 32), LDS_AS(Bs1 + brow * 32), 16, 0, 0);
        }
        __syncthreads();   // staging complete
        short8 af[4], bfr[4];
        // k half 0
#pragma unroll
        for (int i = 0; i < 4; ++i) {
            af[i]  = *(const short8*)&As0[(wm + i * 16 + lrow) * 32 + lk8];
            bfr[i] = *(const short8*)&Bs0[(wn + i * 16 + lrow) * 32 + lk8];
        }
#pragma unroll
        for (int i = 0; i < 4; ++i)
#pragma unroll
            for (int j = 0; j < 4; ++j)
                acc[i][j] = __builtin_amdgcn_mfma_f32_16x16x32_bf16(
                    af[i], bfr[j], acc[i][j], 0, 0, 0);
        // k half 1
#pragma unroll
        for (int i = 0; i < 4; ++i) {
            af[i]  = *(const short8*)&As1[(wm + i * 16 + lrow) * 32 + lk8];
            bfr[i] = *(const short8*)&Bs1[(wn + i * 16 + lrow) * 32 + lk8];
        }
#pragma unroll
        for (int i = 0; i < 4; ++i)
#pragma unroll
            for (int j = 0; j < 4; ++j)
                acc[i][j] = __builtin_amdgcn_mfma_f32_16x16x32_bf16(
                    af[i], bfr[j], acc[i][j], 0, 0, 0);
    }

    const int r4 = (lane >> 4) * 4;
#pragma unroll
    for (int i = 0; i < 4; ++i) {
#pragma unroll
        for (int r = 0; r < 4; ++r) {
            int grow = m0 + wm + i * 16 + r4 + r;
#pragma unroll
            for (int j = 0; j < 4; ++j) {
                int gcol = n0 + wn + j * 16 + lrow;
                float v  = fmaxf(acc[i][j][r] + bias[gcol], 0.0f);
                C[(size_t)grow * QKV_LD + gcol] = __float2bfloat16(v);
            }
        }
    }
}

// ---------------------------------------------------------------------------
// 256x128-tile bf16 GEMM (verified rounds 13/15; FFNs): 512 threads, 8 waves,
// BK=64 dual-buffer global_load_lds staging, n-fastest XCD swizzle. 48 KB LDS.
template<int OUTF32, int RELU>
__global__ __launch_bounds__(512) void gemm_lds256(
    const bf16* __restrict__ A, int lda,
    const bf16* __restrict__ Bt, int ldb,
    const float* __restrict__ bias, void* __restrict__ Cv,
    int Mvalid, int Kdim, int ldc, int nby)
{
    __shared__ alignas(16) bf16 As0[256 * 32];
    __shared__ alignas(16) bf16 As1[256 * 32];
    __shared__ alignas(16) bf16 Bs0[128 * 32];
    __shared__ alignas(16) bf16 Bs1[128 * 32];
    const int cpx = gridDim.x >> 3;
    const int swz = (blockIdx.x & 7) * cpx + (blockIdx.x >> 3);
    const int m0 = (swz / nby) * 256;
    const int n0 = (swz % nby) * 128;
    const int t = threadIdx.x, wave = t >> 6, lane = t & 63;
    const int wm = (wave >> 1) * 64, wn = (wave & 1) * 64;
    const int lrow = lane & 15, lk8 = (lane >> 4) * 8;
    const int srow = lane >> 2, scol = (lane & 3) << 3;
    f32x4 acc[4][4] = {};
    const int nk = Kdim >> 6;                // BK = 64

    for (int ks = 0; ks < nk; ++ks) {
        const int kk = ks << 6;
        __syncthreads();
#pragma unroll
        for (int c = 0; c < 2; ++c) {
            const int arow = wave * 32 + c * 16;
            const bf16* ga = A + (size_t)(m0 + arow + srow) * lda + kk + scol;
            __builtin_amdgcn_global_load_lds(GLOBAL_AS(ga),      LDS_AS(As0 + arow * 32), 16, 0, 0);
            __builtin_amdgcn_global_load_lds(GLOBAL_AS(ga + 32), LDS_AS(As1 + arow * 32), 16, 0, 0);
        }
        {
            const int brow = wave * 16;
            const bf16* gb = Bt + (size_t)(n0 + brow + srow) * ldb + kk + scol;
            __builtin_amdgcn_global_load_lds(GLOBAL_AS(gb),      LDS_AS(Bs0 + brow * 32), 16, 0, 0);
            __builtin_amdgcn_global_load_lds(GLOBAL_AS(gb + 32), LDS_AS(Bs1 + brow * 32), 16, 0, 0);
        }
        __syncthreads();
        short8 af[4], bfr[4];
#pragma unroll
        for (int i = 0; i < 4; ++i) {
            af[i]  = *(const short8*)&As0[(wm + i * 16 + lrow) * 32 + lk8];
            bfr[i] = *(const short8*)&Bs0[(wn + i * 16 + lrow) * 32 + lk8];
        }
#pragma unroll
        for (int i = 0; i < 4; ++i)
#pragma unroll
            for (int j = 0; j < 4; ++j)
                acc[i][j] = __builtin_amdgcn_mfma_f32_16x16x32_bf16(
                    af[i], bfr[j], acc[i][j], 0, 0, 0);
#pragma unroll
        for (int i = 0; i < 4; ++i) {
            af[i]  = *(const short8*)&As1[(wm + i * 16 + lrow) * 32 + lk8];
            bfr[i] = *(const short8*)&Bs1[(wn + i * 16 + lrow) * 32 + lk8];
        }
#pragma unroll
        for (int i = 0; i < 4; ++i)
#pragma unroll
            for (int j = 0; j < 4; ++j)
                acc[i][j] = __builtin_amdgcn_mfma_f32_16x16x32_bf16(
                    af[i], bfr[j], acc[i][j], 0, 0, 0);
    }

    const int r4 = (lane >> 4) * 4;
#pragma unroll
    for (int i = 0; i < 4; ++i) {
#pragma unroll
        for (int r = 0; r < 4; ++r) {
            int grow = m0 + wm + i * 16 + r4 + r;
            if (OUTF32 && grow >= Mvalid) continue;
#pragma unroll
            for (int j = 0; j < 4; ++j) {
                int gcol = n0 + wn + j * 16 + lrow;
                float v  = acc[i][j][r] + bias[gcol];
                if (RELU) v = fmaxf(v, 0.0f);
                if (OUTF32)
                    ((float*)Cv)[(size_t)grow * ldc + gcol] = v;
                else
                    ((bf16*)Cv)[(size_t)grow * ldc + gcol] = __float2bfloat16(v);
            }
        }
    }
}

// ---------------------------------------------------------------------------
// Attention v4.1 (verified rounds 11/13/15, unchanged): one block per (bt,h),
// 512 threads (8 waves), zero main-loop barriers; wave w owns tiles w, w+8,
// then balanced third pass tile=20-w for waves 0-4. K resident [336][72],
// V transposed [64][354] in LDS; scores+softmax in registers; PV via
// per-wave LDS transpose chunk. LDS = 104 KB.
#define KS_LD  72
#define VT_LD  354
__global__ __launch_bounds__(512) void attn_kernel(
    bf16* __restrict__ qkv, float* __restrict__ attn_out)
{
    __shared__ alignas(16) bf16 Ks[336 * KS_LD];        // 48384 B
    __shared__ alignas(16) bf16 Vt[64 * VT_LD + 32];    // 45376 B
    __shared__ alignas(16) bf16 ptile[8][16 * 40];      // 10240 B
    const int t = threadIdx.x, lane = t & 63, w = t >> 6;
    const int h = blockIdx.x & 7, bt = blockIdx.x >> 3;
    const size_t rowbase = (size_t)bt * N_TOK;
    const int lrow = lane & 15, lk8 = (lane >> 4) * 8;
    const int r4 = (lane >> 4) * 4;
    const int b = bt / 12, tt2 = bt % 12;
    const size_t hb_base = (((size_t)(h * 8 + b)) * 12 + tt2) * N_TOK;

    for (int task = t; task < 336 * 8; task += 512) {
        int m = task >> 3, e0 = (task & 7) << 3;
        short8 v = {0, 0, 0, 0, 0, 0, 0, 0};
        if (m < N_TOK)
            v = *(const short8*)(qkv + (rowbase + m) * QKV_LD + 512 + h * 64 + e0);
        *(short8*)&Ks[m * KS_LD + e0] = v;
    }
    for (int task = t; task < 352 * 8; task += 512) {
        int m = task >> 3, e0 = (task & 7) << 3;
        short8 v = {0, 0, 0, 0, 0, 0, 0, 0};
        if (m < N_TOK)
            v = *(const short8*)(qkv + (rowbase + m) * QKV_LD + 1024 + h * 64 + e0);
#pragma unroll
        for (int j = 0; j < 8; ++j)
            Vt[(e0 + j) * VT_LD + m] = ((bf16*)&v)[j];
    }
    __syncthreads();   // the only block-wide barrier

    for (int it = 0; it < 3; ++it) {
        if (it == 2 && w > 4) break;
        const int tile = (it < 2) ? (w + it * 8) : (20 - w);   // wave-uniform
        const int r0 = tile * 16;

        int qrow = r0 + lrow; if (qrow > N_TOK - 1) qrow = N_TOK - 1;
        const bf16* qp = qkv + (rowbase + qrow) * QKV_LD + h * 64 + lk8;
        short8 qa0 = *(const short8*)(qp);
        short8 qa1 = *(const short8*)(qp + 32);

        f32x4 f[22];
        f[21] = (f32x4){0.f, 0.f, 0.f, 0.f};
#pragma unroll
        for (int ct = 0; ct < 21; ++ct) {
            if (ct <= tile) {                 // wave-uniform branch
                f32x4 a = {0.f, 0.f, 0.f, 0.f};
                short8 kb0 = *(const short8*)&Ks[(ct * 16 + lrow) * KS_LD + lk8];
                short8 kb1 = *(const short8*)&Ks[(ct * 16 + lrow) * KS_LD + 32 + lk8];
                a = __builtin_amdgcn_mfma_f32_16x16x32_bf16(qa0, kb0, a, 0, 0, 0);
                a = __builtin_amdgcn_mfma_f32_16x16x32_bf16(qa1, kb1, a, 0, 0, 0);
                f[ct] = a;
            }
        }

        float mx[4] = {-1e30f, -1e30f, -1e30f, -1e30f};
        float sm[4] = {0.f, 0.f, 0.f, 0.f};
#pragma unroll
        for (int ct = 0; ct < 21; ++ct) {
            if (ct <= tile) {
                const int c = ct * 16 + lrow;
#pragma unroll
                for (int r = 0; r < 4; ++r)
                    if (c <= r0 + r4 + r) mx[r] = fmaxf(mx[r], f[ct][r]);
            }
        }
#pragma unroll
        for (int r = 0; r < 4; ++r) {
#pragma unroll
            for (int o = 1; o < 16; o <<= 1) mx[r] = fmaxf(mx[r], __shfl_xor(mx[r], o));
        }
#pragma unroll
        for (int ct = 0; ct < 21; ++ct) {
            if (ct <= tile) {
                const int c = ct * 16 + lrow;
#pragma unroll
                for (int r = 0; r < 4; ++r) {
                    float e = (c <= r0 + r4 + r)
                                  ? __expf((f[ct][r] - mx[r]) * 0.125f) : 0.f;
                    f[ct][r] = e;
                    sm[r] += e;
                }
            }
        }
#pragma unroll
        for (int r = 0; r < 4; ++r) {
#pragma unroll
            for (int o = 1; o < 16; o <<= 1) sm[r] += __shfl_xor(sm[r], o);
            sm[r] = 1.0f / sm[r];
        }
#pragma unroll
        for (int ct = 0; ct < 21; ++ct) {
            if (ct <= tile) {
#pragma unroll
                for (int r = 0; r < 4; ++r) f[ct][r] *= sm[r];
            }
        }

#pragma unroll
        for (int ct = 0; ct < 21; ++ct) {
            const int c = ct * 16 + lrow;
            if (c < N_TOK) {
#pragma unroll
                for (int r = 0; r < 4; ++r) {
                    const int n = r0 + r4 + r;
                    if (n < N_TOK) {
                        float v = (ct <= tile && c <= n) ? f[ct][r] : 0.f;
                        attn_out[(hb_base + n) * N_TOK + c] = v;
                    }
                }
            }
        }

        f32x4 acc[4] = {};
        bf16* pt = &ptile[w][0];
#pragma unroll
        for (int s = 0; s < 11; ++s) {
            if (s <= (tile >> 1)) {           // wave-uniform
#pragma unroll
                for (int half = 0; half < 2; ++half) {
                    const int ct2 = 2 * s + half;
                    const int c = ct2 * 16 + lrow;
#pragma unroll
                    for (int r = 0; r < 4; ++r) {
                        const int n = r0 + r4 + r;
                        float v = (ct2 <= tile && c <= n) ? f[ct2][r] : 0.f;
                        pt[(r4 + r) * 40 + half * 16 + lrow] = __float2bfloat16(v);
                    }
                }
                short8 aa = *(const short8*)&pt[lrow * 40 + lk8];
#pragma unroll
                for (int e = 0; e < 4; ++e) {
                    short8 bb = *(const short8*)&Vt[(e * 16 + lrow) * VT_LD + s * 32 + lk8];
                    acc[e] = __builtin_amdgcn_mfma_f32_16x16x32_bf16(aa, bb, acc[e], 0, 0, 0);
                }
            }
        }

#pragma unroll
        for (int e = 0; e < 4; ++e) {
#pragma unroll
            for (int r = 0; r < 4; ++r) {
                const int n = r0 + r4 + r;
                if (n < N_TOK)
                    qkv[(rowbase + n) * QKV_LD + h * 64 + e * 16 + lrow] =
                        __float2bfloat16(acc[e][r]);
            }
        }
    }
}

// ---------------------------------------------------------------------------
extern "C" void kernel_launch(void* const* d_in, const int* in_sizes, int n_in,
                              void* d_out, int out_size, void* d_ws, size_t ws_size,
                              hipStream_t stream)
{
    const void* X   = d_in[0];
    const void* STE = d_in[1];
    const void* Wq  = d_in[2];
    const void* bq  = d_in[3];
    const void* Wk  = d_in[4];
    const void* bk  = d_in[5];
    const void* Wv  = d_in[6];
    const void* bv  = d_in[7];
    const void* W1  = d_in[8];
    const void* b1  = d_in[9];
    const void* W2  = d_in[10];
    const void* b2  = d_in[11];

    float* out0     = (float*)d_out;                              // [31200][512] f32
    float* attn_out = (float*)d_out + (size_t)M_ROWS * D_MODEL;   // [64][12][325][325] f32

    char* ws = (char*)d_ws;
    bf16*  qkv   = (bf16*)(ws);                      // 31232*1536*2 = 95,944,704
    bf16*  BtQKV = (bf16*)(ws + 95944704);           //  3,145,728
    bf16*  W1T   = (bf16*)(ws + 99090432);           //    524,288
    bf16*  W2T   = (bf16*)(ws + 99614720);           //    524,288
    float* biasQ = (float*)(ws + 100139008);         //      6,144
    float* b1f   = (float*)(ws + 100145152);         //      2,048
    float* b2f   = (float*)(ws + 100147200);         //      2,048
    int*   flag  = (int*)(ws + 100149248);           //          4
    bf16*  hbuf  = qkv + 512;                        // FFN hidden aliases k-slice

    init_flag<<<1, 64, 0, stream>>>(flag);
    detect_dtype<<<64, 256, 0, stream>>>((const unsigned short*)X, flag);

    transpose_w_tiled<<<dim3(16, 32), 256, 0, stream>>>(Wq, BtQKV, 1024, 512, flag);
    transpose_w_tiled<<<dim3(16, 32), 256, 0, stream>>>(Wk, BtQKV + 512 * 1024, 1024, 512, flag);
    transpose_w_tiled<<<dim3(16, 32), 256, 0, stream>>>(Wv, BtQKV + 1024 * 1024, 1024, 512, flag);
    transpose_w_tiled<<<dim3(16, 16), 256, 0, stream>>>(W1, W1T, 512, 512, flag);
    transpose_w_tiled<<<dim3(16, 16), 256, 0, stream>>>(W2, W2T, 512, 512, flag);
    prep_bias<<<2, 256, 0, stream>>>(bq, bk, bv, b1, b2, biasQ, b1f, b2f, flag);

    // Fused QKV projection: concat(X,STE) @ BtQKV^T -> qkv (+bias, relu)
    gemm_qkv<<<122 * 12, 512, 0, stream>>>(X, STE, BtQKV, biasQ, qkv, flag);

    // attention (ctx -> q-slice of qkv; attn -> f32 d_out region)
    attn_kernel<<<768, 512, 0, stream>>>(qkv, attn_out);

    // FFN1: relu(ctx @ W1 + b1) -> hbuf (k-slice of qkv)
    gemm_lds256<0, 1><<<122 * 4, 512, 0, stream>>>(
        qkv, QKV_LD, W1T, 512, b1f, hbuf, M_PAD, 512, QKV_LD, 4);

    // FFN2: hbuf @ W2 + b2 -> out0 (f32, guarded at M_ROWS)
    gemm_lds256<1, 0><<<122 * 4, 512, 0, stream>>>(
        hbuf, QKV_LD, W2T, 512, b2f, out0, M_ROWS, 512, D_MODEL, 4);
}

// Round 17
// 365.139 us; speedup vs baseline: 1.1308x; 1.1308x over previous
//
#include <hip/hip_runtime.h>
#include <hip/hip_bf16.h>

typedef __hip_bfloat16 bf16;
using f32x4  = __attribute__((ext_vector_type(4))) float;
using short8 = __attribute__((ext_vector_type(8))) short;

// B=8, T=12, N=325, K=8 heads, d=64, D=512, BT=96, M=31200 (padded 31232)
#define M_ROWS   31200
#define M_PAD    31232
#define N_TOK    325
#define D_MODEL  512
#define QKV_LD   1536

#define GLOBAL_AS(p) ((const __attribute__((address_space(1))) unsigned int*)(p))
#define LDS_AS(p)    ((__attribute__((address_space(3))) unsigned int*)(p))

// ---------------------------------------------------------------------------
// dtype detection: device inputs are either f32 or bf16 (flag=1 -> f32).
__global__ void init_flag(int* flag) { if (threadIdx.x == 0) *flag = 0; }

__global__ void detect_dtype(const unsigned short* __restrict__ x, int* flag)
{
    int i = blockIdx.x * 256 + threadIdx.x;   // 64 blocks * 256 = 16384 halves
    unsigned short h = x[i];
    int e = (h >> 7) & 0xFF;
    if (e >= 135) atomicOr(flag, 1);
}

__device__ __forceinline__ float load_in(const void* p, size_t i, bool f32)
{
    return f32 ? ((const float*)p)[i] : __bfloat162float(((const bf16*)p)[i]);
}

// ---------------------------------------------------------------------------
// concat(X,STE) -> bf16 Xc[31232][1024]; rows >= 31200 zeroed.
__global__ void concat_cast(const void* __restrict__ X, const void* __restrict__ STE,
                            bf16* __restrict__ Xc, const int* __restrict__ flag)
{
    const bool f32 = (*flag != 0);
    int idx = blockIdx.x * 256 + threadIdx.x;       // M_PAD*128 tasks of 8 elems
    int r = idx >> 7, c8 = (idx & 127) << 3;
    short8 v = {0, 0, 0, 0, 0, 0, 0, 0};
    if (r < M_ROWS) {
        const void* src = (c8 < 512) ? X : STE;
        int cc = c8 & 511;
        if (f32) {
            const float* s = (const float*)src + (size_t)r * 512 + cc;
            float4 a = *(const float4*)s;
            float4 b = *(const float4*)(s + 4);
            ((bf16*)&v)[0] = __float2bfloat16(a.x); ((bf16*)&v)[1] = __float2bfloat16(a.y);
            ((bf16*)&v)[2] = __float2bfloat16(a.z); ((bf16*)&v)[3] = __float2bfloat16(a.w);
            ((bf16*)&v)[4] = __float2bfloat16(b.x); ((bf16*)&v)[5] = __float2bfloat16(b.y);
            ((bf16*)&v)[6] = __float2bfloat16(b.z); ((bf16*)&v)[7] = __float2bfloat16(b.w);
        } else {
            v = *(const short8*)((const bf16*)src + (size_t)r * 512 + cc);
        }
    }
    *(short8*)&Xc[(size_t)r * 1024 + c8] = v;
}

// ---------------------------------------------------------------------------
// batched tiled transpose of all 5 weights in ONE launch (saves 4 launch
// gaps). Blocks 0..1535: Wq/Wk/Wv (1024x512, 16x32 tiles each); blocks
// 1536..2047: W1/W2 (512x512, 16x16 tiles each). Same verified 32x32
// LDS-tile body as rounds 5-15.
__global__ void transpose_w_all(
    const void* __restrict__ Wq, const void* __restrict__ Wk,
    const void* __restrict__ Wv, const void* __restrict__ W1,
    const void* __restrict__ W2, bf16* __restrict__ BtQKV,
    bf16* __restrict__ W1T, bf16* __restrict__ W2T,
    const int* __restrict__ flag)
{
    __shared__ float tile[32][33];
    const bool f32 = (*flag != 0);
    const int bid = blockIdx.x;
    const void* src;
    bf16* dst;
    int krows, tile_id;
    if (bid < 1536) {
        const int wsel = bid / 512;              // 0:Wq 1:Wk 2:Wv
        tile_id = bid % 512;                     // 16 x 32 tile grid
        src = (wsel == 0) ? Wq : ((wsel == 1) ? Wk : Wv);
        dst = BtQKV + (size_t)wsel * 512 * 1024;
        krows = 1024;
    } else {
        const int wsel = (bid - 1536) / 256;     // 0:W1 1:W2
        tile_id = (bid - 1536) % 256;            // 16 x 16 tile grid
        src = (wsel == 0) ? W1 : W2;
        dst = (wsel == 0) ? W1T : W2T;
        krows = 512;
    }
    const int ncols = 512;
    const int nt = (tile_id % 16) * 32;          // col tile
    const int kt = (tile_id / 16) * 32;          // row tile
    const int tx = threadIdx.x & 31, ty = threadIdx.x >> 5;   // 32 x 8
#pragma unroll
    for (int r = 0; r < 32; r += 8)
        tile[ty + r][tx] = load_in(src, (size_t)(kt + ty + r) * ncols + (nt + tx), f32);
    __syncthreads();
#pragma unroll
    for (int r = 0; r < 32; r += 8)
        dst[(size_t)(nt + ty + r) * krows + (kt + tx)] = __float2bfloat16(tile[tx][ty + r]);
}

__global__ void prep_bias(const void* __restrict__ bq, const void* __restrict__ bk,
                          const void* __restrict__ bv, const void* __restrict__ b1,
                          const void* __restrict__ b2,
                          float* __restrict__ biasQKV, float* __restrict__ b1f,
                          float* __restrict__ b2f, const int* __restrict__ flag)
{
    const bool f32 = (*flag != 0);
    int i = blockIdx.x * 256 + threadIdx.x;
    if (i < 512) {
        biasQKV[i]        = load_in(bq, i, f32);
        biasQKV[512 + i]  = load_in(bk, i, f32);
        biasQKV[1024 + i] = load_in(bv, i, f32);
        b1f[i] = load_in(b1, i, f32);
        b2f[i] = load_in(b2, i, f32);
    }
}

// ---------------------------------------------------------------------------
// 256x128-tile bf16 GEMM (verified rounds 13/15; all GEMMs): 512 threads,
// 8 waves (4x2 of 64x64 wave-tiles), BK=64 dual-buffer global_load_lds
// staging, n-fastest XCD-swizzled tile order. LDS 48 KB.
template<int OUTF32, int RELU>
__global__ __launch_bounds__(512) void gemm_lds256(
    const bf16* __restrict__ A, int lda,
    const bf16* __restrict__ Bt, int ldb,
    const float* __restrict__ bias, void* __restrict__ Cv,
    int Mvalid, int Kdim, int ldc, int nby)
{
    __shared__ alignas(16) bf16 As0[256 * 32];
    __shared__ alignas(16) bf16 As1[256 * 32];
    __shared__ alignas(16) bf16 Bs0[128 * 32];
    __shared__ alignas(16) bf16 Bs1[128 * 32];
    const int cpx = gridDim.x >> 3;
    const int swz = (blockIdx.x & 7) * cpx + (blockIdx.x >> 3);
    const int m0 = (swz / nby) * 256;
    const int n0 = (swz % nby) * 128;
    const int t = threadIdx.x, wave = t >> 6, lane = t & 63;
    const int wm = (wave >> 1) * 64, wn = (wave & 1) * 64;
    const int lrow = lane & 15, lk8 = (lane >> 4) * 8;
    const int srow = lane >> 2, scol = (lane & 3) << 3;
    f32x4 acc[4][4] = {};
    const int nk = Kdim >> 6;                // BK = 64

    for (int ks = 0; ks < nk; ++ks) {
        const int kk = ks << 6;
        __syncthreads();
#pragma unroll
        for (int c = 0; c < 2; ++c) {
            const int arow = wave * 32 + c * 16;
            const bf16* ga = A + (size_t)(m0 + arow + srow) * lda + kk + scol;
            __builtin_amdgcn_global_load_lds(GLOBAL_AS(ga),      LDS_AS(As0 + arow * 32), 16, 0, 0);
            __builtin_amdgcn_global_load_lds(GLOBAL_AS(ga + 32), LDS_AS(As1 + arow * 32), 16, 0, 0);
        }
        {
            const int brow = wave * 16;
            const bf16* gb = Bt + (size_t)(n0 + brow + srow) * ldb + kk + scol;
            __builtin_amdgcn_global_load_lds(GLOBAL_AS(gb),      LDS_AS(Bs0 + brow * 32), 16, 0, 0);
            __builtin_amdgcn_global_load_lds(GLOBAL_AS(gb + 32), LDS_AS(Bs1 + brow * 32), 16, 0, 0);
        }
        __syncthreads();
        short8 af[4], bfr[4];
#pragma unroll
        for (int i = 0; i < 4; ++i) {
            af[i]  = *(const short8*)&As0[(wm + i * 16 + lrow) * 32 + lk8];
            bfr[i] = *(const short8*)&Bs0[(wn + i * 16 + lrow) * 32 + lk8];
        }
#pragma unroll
        for (int i = 0; i < 4; ++i)
#pragma unroll
            for (int j = 0; j < 4; ++j)
                acc[i][j] = __builtin_amdgcn_mfma_f32_16x16x32_bf16(
                    af[i], bfr[j], acc[i][j], 0, 0, 0);
#pragma unroll
        for (int i = 0; i < 4; ++i) {
            af[i]  = *(const short8*)&As1[(wm + i * 16 + lrow) * 32 + lk8];
            bfr[i] = *(const short8*)&Bs1[(wn + i * 16 + lrow) * 32 + lk8];
        }
#pragma unroll
        for (int i = 0; i < 4; ++i)
#pragma unroll
            for (int j = 0; j < 4; ++j)
                acc[i][j] = __builtin_amdgcn_mfma_f32_16x16x32_bf16(
                    af[i], bfr[j], acc[i][j], 0, 0, 0);
    }

    const int r4 = (lane >> 4) * 4;
#pragma unroll
    for (int i = 0; i < 4; ++i) {
#pragma unroll
        for (int r = 0; r < 4; ++r) {
            int grow = m0 + wm + i * 16 + r4 + r;
            if (OUTF32 && grow >= Mvalid) continue;
#pragma unroll
            for (int j = 0; j < 4; ++j) {
                int gcol = n0 + wn + j * 16 + lrow;
                float v  = acc[i][j][r] + bias[gcol];
                if (RELU) v = fmaxf(v, 0.0f);
                if (OUTF32)
                    ((float*)Cv)[(size_t)grow * ldc + gcol] = v;
                else
                    ((bf16*)Cv)[(size_t)grow * ldc + gcol] = __float2bfloat16(v);
            }
        }
    }
}

// ---------------------------------------------------------------------------
// Attention v4.1 (verified rounds 11/13/15, unchanged): one block per (bt,h),
// 512 threads (8 waves), zero main-loop barriers; wave w owns tiles w, w+8,
// then balanced third pass tile=20-w for waves 0-4. K resident [336][72],
// V transposed [64][354] in LDS; scores+softmax in registers; PV via
// per-wave LDS transpose chunk. LDS = 104 KB.
#define KS_LD  72
#define VT_LD  354
__global__ __launch_bounds__(512) void attn_kernel(
    bf16* __restrict__ qkv, float* __restrict__ attn_out)
{
    __shared__ alignas(16) bf16 Ks[336 * KS_LD];        // 48384 B
    __shared__ alignas(16) bf16 Vt[64 * VT_LD + 32];    // 45376 B
    __shared__ alignas(16) bf16 ptile[8][16 * 40];      // 10240 B
    const int t = threadIdx.x, lane = t & 63, w = t >> 6;
    const int h = blockIdx.x & 7, bt = blockIdx.x >> 3;
    const size_t rowbase = (size_t)bt * N_TOK;
    const int lrow = lane & 15, lk8 = (lane >> 4) * 8;
    const int r4 = (lane >> 4) * 4;
    const int b = bt / 12, tt2 = bt % 12;
    const size_t hb_base = (((size_t)(h * 8 + b)) * 12 + tt2) * N_TOK;

    for (int task = t; task < 336 * 8; task += 512) {
        int m = task >> 3, e0 = (task & 7) << 3;
        short8 v = {0, 0, 0, 0, 0, 0, 0, 0};
        if (m < N_TOK)
            v = *(const short8*)(qkv + (rowbase + m) * QKV_LD + 512 + h * 64 + e0);
        *(short8*)&Ks[m * KS_LD + e0] = v;
    }
    for (int task = t; task < 352 * 8; task += 512) {
        int m = task >> 3, e0 = (task & 7) << 3;
        short8 v = {0, 0, 0, 0, 0, 0, 0, 0};
        if (m < N_TOK)
            v = *(const short8*)(qkv + (rowbase + m) * QKV_LD + 1024 + h * 64 + e0);
#pragma unroll
        for (int j = 0; j < 8; ++j)
            Vt[(e0 + j) * VT_LD + m] = ((bf16*)&v)[j];
    }
    __syncthreads();   // the only block-wide barrier

    for (int it = 0; it < 3; ++it) {
        if (it == 2 && w > 4) break;
        const int tile = (it < 2) ? (w + it * 8) : (20 - w);   // wave-uniform
        const int r0 = tile * 16;

        int qrow = r0 + lrow; if (qrow > N_TOK - 1) qrow = N_TOK - 1;
        const bf16* qp = qkv + (rowbase + qrow) * QKV_LD + h * 64 + lk8;
        short8 qa0 = *(const short8*)(qp);
        short8 qa1 = *(const short8*)(qp + 32);

        f32x4 f[22];
        f[21] = (f32x4){0.f, 0.f, 0.f, 0.f};
#pragma unroll
        for (int ct = 0; ct < 21; ++ct) {
            if (ct <= tile) {                 // wave-uniform branch
                f32x4 a = {0.f, 0.f, 0.f, 0.f};
                short8 kb0 = *(const short8*)&Ks[(ct * 16 + lrow) * KS_LD + lk8];
                short8 kb1 = *(const short8*)&Ks[(ct * 16 + lrow) * KS_LD + 32 + lk8];
                a = __builtin_amdgcn_mfma_f32_16x16x32_bf16(qa0, kb0, a, 0, 0, 0);
                a = __builtin_amdgcn_mfma_f32_16x16x32_bf16(qa1, kb1, a, 0, 0, 0);
                f[ct] = a;
            }
        }

        float mx[4] = {-1e30f, -1e30f, -1e30f, -1e30f};
        float sm[4] = {0.f, 0.f, 0.f, 0.f};
#pragma unroll
        for (int ct = 0; ct < 21; ++ct) {
            if (ct <= tile) {
                const int c = ct * 16 + lrow;
#pragma unroll
                for (int r = 0; r < 4; ++r)
                    if (c <= r0 + r4 + r) mx[r] = fmaxf(mx[r], f[ct][r]);
            }
        }
#pragma unroll
        for (int r = 0; r < 4; ++r) {
#pragma unroll
            for (int o = 1; o < 16; o <<= 1) mx[r] = fmaxf(mx[r], __shfl_xor(mx[r], o));
        }
#pragma unroll
        for (int ct = 0; ct < 21; ++ct) {
            if (ct <= tile) {
                const int c = ct * 16 + lrow;
#pragma unroll
                for (int r = 0; r < 4; ++r) {
                    float e = (c <= r0 + r4 + r)
                                  ? __expf((f[ct][r] - mx[r]) * 0.125f) : 0.f;
                    f[ct][r] = e;
                    sm[r] += e;
                }
            }
        }
#pragma unroll
        for (int r = 0; r < 4; ++r) {
#pragma unroll
            for (int o = 1; o < 16; o <<= 1) sm[r] += __shfl_xor(sm[r], o);
            sm[r] = 1.0f / sm[r];
        }
#pragma unroll
        for (int ct = 0; ct < 21; ++ct) {
            if (ct <= tile) {
#pragma unroll
                for (int r = 0; r < 4; ++r) f[ct][r] *= sm[r];
            }
        }

#pragma unroll
        for (int ct = 0; ct < 21; ++ct) {
            const int c = ct * 16 + lrow;
            if (c < N_TOK) {
#pragma unroll
                for (int r = 0; r < 4; ++r) {
                    const int n = r0 + r4 + r;
                    if (n < N_TOK) {
                        float v = (ct <= tile && c <= n) ? f[ct][r] : 0.f;
                        attn_out[(hb_base + n) * N_TOK + c] = v;
                    }
                }
            }
        }

        f32x4 acc[4] = {};
        bf16* pt = &ptile[w][0];
#pragma unroll
        for (int s = 0; s < 11; ++s) {
            if (s <= (tile >> 1)) {           // wave-uniform
#pragma unroll
                for (int half = 0; half < 2; ++half) {
                    const int ct2 = 2 * s + half;
                    const int c = ct2 * 16 + lrow;
#pragma unroll
                    for (int r = 0; r < 4; ++r) {
                        const int n = r0 + r4 + r;
                        float v = (ct2 <= tile && c <= n) ? f[ct2][r] : 0.f;
                        pt[(r4 + r) * 40 + half * 16 + lrow] = __float2bfloat16(v);
                    }
                }
                short8 aa = *(const short8*)&pt[lrow * 40 + lk8];
#pragma unroll
                for (int e = 0; e < 4; ++e) {
                    short8 bb = *(const short8*)&Vt[(e * 16 + lrow) * VT_LD + s * 32 + lk8];
                    acc[e] = __builtin_amdgcn_mfma_f32_16x16x32_bf16(aa, bb, acc[e], 0, 0, 0);
                }
            }
        }

#pragma unroll
        for (int e = 0; e < 4; ++e) {
#pragma unroll
            for (int r = 0; r < 4; ++r) {
                const int n = r0 + r4 + r;
                if (n < N_TOK)
                    qkv[(rowbase + n) * QKV_LD + h * 64 + e * 16 + lrow] =
                        __float2bfloat16(acc[e][r]);
            }
        }
    }
}

// ---------------------------------------------------------------------------
extern "C" void kernel_launch(void* const* d_in, const int* in_sizes, int n_in,
                              void* d_out, int out_size, void* d_ws, size_t ws_size,
                              hipStream_t stream)
{
    const void* X   = d_in[0];
    const void* STE = d_in[1];
    const void* Wq  = d_in[2];
    const void* bq  = d_in[3];
    const void* Wk  = d_in[4];
    const void* bk  = d_in[5];
    const void* Wv  = d_in[6];
    const void* bv  = d_in[7];
    const void* W1  = d_in[8];
    const void* b1  = d_in[9];
    const void* W2  = d_in[10];
    const void* b2  = d_in[11];

    float* out0     = (float*)d_out;                              // [31200][512] f32
    float* attn_out = (float*)d_out + (size_t)M_ROWS * D_MODEL;   // [64][12][325][325] f32
    bf16*  Xc       = (bf16*)attn_out;   // scratch; overwritten by attn_kernel later

    char* ws = (char*)d_ws;
    bf16*  qkv   = (bf16*)(ws);                      // 31232*1536*2 = 95,944,704
    bf16*  BtQKV = (bf16*)(ws + 95944704);           //  3,145,728
    bf16*  W1T   = (bf16*)(ws + 99090432);           //    524,288
    bf16*  W2T   = (bf16*)(ws + 99614720);           //    524,288
    float* biasQ = (float*)(ws + 100139008);         //      6,144
    float* b1f   = (float*)(ws + 100145152);         //      2,048
    float* b2f   = (float*)(ws + 100147200);         //      2,048
    int*   flag  = (int*)(ws + 100149248);           //          4
    bf16*  hbuf  = qkv + 512;                        // FFN hidden aliases k-slice

    init_flag<<<1, 64, 0, stream>>>(flag);
    detect_dtype<<<64, 256, 0, stream>>>((const unsigned short*)X, flag);

    // all 5 weight transposes in one launch
    transpose_w_all<<<2048, 256, 0, stream>>>(Wq, Wk, Wv, W1, W2,
                                              BtQKV, W1T, W2T, flag);
    prep_bias<<<2, 256, 0, stream>>>(bq, bk, bv, b1, b2, biasQ, b1f, b2f, flag);

    // concat(X,STE) -> bf16 Xc [31232][1024]
    concat_cast<<<(M_PAD * 128) / 256, 256, 0, stream>>>(X, STE, Xc, flag);

    // QKV projection: Xc[31232,1024] @ BtQKV^T -> qkv (+bias, relu)
    gemm_lds256<0, 1><<<122 * 12, 512, 0, stream>>>(
        Xc, 1024, BtQKV, 1024, biasQ, qkv, M_PAD, 1024, QKV_LD, 12);

    // attention (ctx -> q-slice of qkv; attn -> f32 d_out region, overwrites Xc)
    attn_kernel<<<768, 512, 0, stream>>>(qkv, attn_out);

    // FFN1: relu(ctx @ W1 + b1) -> hbuf (k-slice of qkv)
    gemm_lds256<0, 1><<<122 * 4, 512, 0, stream>>>(
        qkv, QKV_LD, W1T, 512, b1f, hbuf, M_PAD, 512, QKV_LD, 4);

    // FFN2: hbuf @ W2 + b2 -> out0 (f32, guarded at M_ROWS)
    gemm_lds256<1, 0><<<122 * 4, 512, 0, stream>>>(
        hbuf, QKV_LD, W2T, 512, b2f, out0, M_ROWS, 512, D_MODEL, 4);
}

// Round 18
// 354.815 us; speedup vs baseline: 1.1637x; 1.0291x over previous
//
#include <hip/hip_runtime.h>
#include <hip/hip_bf16.h>

typedef __hip_bfloat16 bf16;
using f32x4  = __attribute__((ext_vector_type(4))) float;
using short8 = __attribute__((ext_vector_type(8))) short;

// B=8, T=12, N=325, K=8 heads, d=64, D=512, BT=96, M=31200 (padded 31232)
#define M_ROWS   31200
#define M_PAD    31232
#define N_TOK    325
#define D_MODEL  512
#define QKV_LD   1536

#define GLOBAL_AS(p) ((const __attribute__((address_space(1))) unsigned int*)(p))
#define LDS_AS(p)    ((__attribute__((address_space(3))) unsigned int*)(p))

// ---------------------------------------------------------------------------
// dtype detection: device inputs are either f32 or bf16 (flag=1 -> f32).
__global__ void init_flag(int* flag) { if (threadIdx.x == 0) *flag = 0; }

__global__ void detect_dtype(const unsigned short* __restrict__ x, int* flag)
{
    int i = blockIdx.x * 256 + threadIdx.x;   // 64 blocks * 256 = 16384 halves
    unsigned short h = x[i];
    int e = (h >> 7) & 0xFF;
    if (e >= 135) atomicOr(flag, 1);
}

__device__ __forceinline__ float load_in(const void* p, size_t i, bool f32)
{
    return f32 ? ((const float*)p)[i] : __bfloat162float(((const bf16*)p)[i]);
}

// ---------------------------------------------------------------------------
// concat(X,STE) -> bf16 Xc[31232][1024]; rows >= 31200 zeroed.
__global__ void concat_cast(const void* __restrict__ X, const void* __restrict__ STE,
                            bf16* __restrict__ Xc, const int* __restrict__ flag)
{
    const bool f32 = (*flag != 0);
    int idx = blockIdx.x * 256 + threadIdx.x;       // M_PAD*128 tasks of 8 elems
    int r = idx >> 7, c8 = (idx & 127) << 3;
    short8 v = {0, 0, 0, 0, 0, 0, 0, 0};
    if (r < M_ROWS) {
        const void* src = (c8 < 512) ? X : STE;
        int cc = c8 & 511;
        if (f32) {
            const float* s = (const float*)src + (size_t)r * 512 + cc;
            float4 a = *(const float4*)s;
            float4 b = *(const float4*)(s + 4);
            ((bf16*)&v)[0] = __float2bfloat16(a.x); ((bf16*)&v)[1] = __float2bfloat16(a.y);
            ((bf16*)&v)[2] = __float2bfloat16(a.z); ((bf16*)&v)[3] = __float2bfloat16(a.w);
            ((bf16*)&v)[4] = __float2bfloat16(b.x); ((bf16*)&v)[5] = __float2bfloat16(b.y);
            ((bf16*)&v)[6] = __float2bfloat16(b.z); ((bf16*)&v)[7] = __float2bfloat16(b.w);
        } else {
            v = *(const short8*)((const bf16*)src + (size_t)r * 512 + cc);
        }
    }
    *(short8*)&Xc[(size_t)r * 1024 + c8] = v;
}

// ---------------------------------------------------------------------------
// batched tiled transpose of all 5 weights in ONE launch (verified round 17).
__global__ void transpose_w_all(
    const void* __restrict__ Wq, const void* __restrict__ Wk,
    const void* __restrict__ Wv, const void* __restrict__ W1,
    const void* __restrict__ W2, bf16* __restrict__ BtQKV,
    bf16* __restrict__ W1T, bf16* __restrict__ W2T,
    const int* __restrict__ flag)
{
    __shared__ float tile[32][33];
    const bool f32 = (*flag != 0);
    const int bid = blockIdx.x;
    const void* src;
    bf16* dst;
    int krows, tile_id;
    if (bid < 1536) {
        const int wsel = bid / 512;              // 0:Wq 1:Wk 2:Wv
        tile_id = bid % 512;                     // 16 x 32 tile grid
        src = (wsel == 0) ? Wq : ((wsel == 1) ? Wk : Wv);
        dst = BtQKV + (size_t)wsel * 512 * 1024;
        krows = 1024;
    } else {
        const int wsel = (bid - 1536) / 256;     // 0:W1 1:W2
        tile_id = (bid - 1536) % 256;            // 16 x 16 tile grid
        src = (wsel == 0) ? W1 : W2;
        dst = (wsel == 0) ? W1T : W2T;
        krows = 512;
    }
    const int ncols = 512;
    const int nt = (tile_id % 16) * 32;          // col tile
    const int kt = (tile_id / 16) * 32;          // row tile
    const int tx = threadIdx.x & 31, ty = threadIdx.x >> 5;   // 32 x 8
#pragma unroll
    for (int r = 0; r < 32; r += 8)
        tile[ty + r][tx] = load_in(src, (size_t)(kt + ty + r) * ncols + (nt + tx), f32);
    __syncthreads();
#pragma unroll
    for (int r = 0; r < 32; r += 8)
        dst[(size_t)(nt + ty + r) * krows + (kt + tx)] = __float2bfloat16(tile[tx][ty + r]);
}

__global__ void prep_bias(const void* __restrict__ bq, const void* __restrict__ bk,
                          const void* __restrict__ bv, const void* __restrict__ b1,
                          const void* __restrict__ b2,
                          float* __restrict__ biasQKV, float* __restrict__ b1f,
                          float* __restrict__ b2f, const int* __restrict__ flag)
{
    const bool f32 = (*flag != 0);
    int i = blockIdx.x * 256 + threadIdx.x;
    if (i < 512) {
        biasQKV[i]        = load_in(bq, i, f32);
        biasQKV[512 + i]  = load_in(bk, i, f32);
        biasQKV[1024 + i] = load_in(bv, i, f32);
        b1f[i] = load_in(b1, i, f32);
        b2f[i] = load_in(b2, i, f32);
    }
}

// ---------------------------------------------------------------------------
// 256x128-tile bf16 GEMM (verified rounds 13/15/17; all GEMMs): 512 threads,
// 8 waves (4x2 of 64x64 wave-tiles), BK=64 dual-buffer global_load_lds
// staging, n-fastest XCD-swizzled tile order. LDS 48 KB.
template<int OUTF32, int RELU>
__global__ __launch_bounds__(512) void gemm_lds256(
    const bf16* __restrict__ A, int lda,
    const bf16* __restrict__ Bt, int ldb,
    const float* __restrict__ bias, void* __restrict__ Cv,
    int Mvalid, int Kdim, int ldc, int nby)
{
    __shared__ alignas(16) bf16 As0[256 * 32];
    __shared__ alignas(16) bf16 As1[256 * 32];
    __shared__ alignas(16) bf16 Bs0[128 * 32];
    __shared__ alignas(16) bf16 Bs1[128 * 32];
    const int cpx = gridDim.x >> 3;
    const int swz = (blockIdx.x & 7) * cpx + (blockIdx.x >> 3);
    const int m0 = (swz / nby) * 256;
    const int n0 = (swz % nby) * 128;
    const int t = threadIdx.x, wave = t >> 6, lane = t & 63;
    const int wm = (wave >> 1) * 64, wn = (wave & 1) * 64;
    const int lrow = lane & 15, lk8 = (lane >> 4) * 8;
    const int srow = lane >> 2, scol = (lane & 3) << 3;
    f32x4 acc[4][4] = {};
    const int nk = Kdim >> 6;                // BK = 64

    for (int ks = 0; ks < nk; ++ks) {
        const int kk = ks << 6;
        __syncthreads();
#pragma unroll
        for (int c = 0; c < 2; ++c) {
            const int arow = wave * 32 + c * 16;
            const bf16* ga = A + (size_t)(m0 + arow + srow) * lda + kk + scol;
            __builtin_amdgcn_global_load_lds(GLOBAL_AS(ga),      LDS_AS(As0 + arow * 32), 16, 0, 0);
            __builtin_amdgcn_global_load_lds(GLOBAL_AS(ga + 32), LDS_AS(As1 + arow * 32), 16, 0, 0);
        }
        {
            const int brow = wave * 16;
            const bf16* gb = Bt + (size_t)(n0 + brow + srow) * ldb + kk + scol;
            __builtin_amdgcn_global_load_lds(GLOBAL_AS(gb),      LDS_AS(Bs0 + brow * 32), 16, 0, 0);
            __builtin_amdgcn_global_load_lds(GLOBAL_AS(gb + 32), LDS_AS(Bs1 + brow * 32), 16, 0, 0);
        }
        __syncthreads();
        short8 af[4], bfr[4];
#pragma unroll
        for (int i = 0; i < 4; ++i) {
            af[i]  = *(const short8*)&As0[(wm + i * 16 + lrow) * 32 + lk8];
            bfr[i] = *(const short8*)&Bs0[(wn + i * 16 + lrow) * 32 + lk8];
        }
#pragma unroll
        for (int i = 0; i < 4; ++i)
#pragma unroll
            for (int j = 0; j < 4; ++j)
                acc[i][j] = __builtin_amdgcn_mfma_f32_16x16x32_bf16(
                    af[i], bfr[j], acc[i][j], 0, 0, 0);
#pragma unroll
        for (int i = 0; i < 4; ++i) {
            af[i]  = *(const short8*)&As1[(wm + i * 16 + lrow) * 32 + lk8];
            bfr[i] = *(const short8*)&Bs1[(wn + i * 16 + lrow) * 32 + lk8];
        }
#pragma unroll
        for (int i = 0; i < 4; ++i)
#pragma unroll
            for (int j = 0; j < 4; ++j)
                acc[i][j] = __builtin_amdgcn_mfma_f32_16x16x32_bf16(
                    af[i], bfr[j], acc[i][j], 0, 0, 0);
    }

    const int r4 = (lane >> 4) * 4;
#pragma unroll
    for (int i = 0; i < 4; ++i) {
#pragma unroll
        for (int r = 0; r < 4; ++r) {
            int grow = m0 + wm + i * 16 + r4 + r;
            if (OUTF32 && grow >= Mvalid) continue;
#pragma unroll
            for (int j = 0; j < 4; ++j) {
                int gcol = n0 + wn + j * 16 + lrow;
                float v  = acc[i][j][r] + bias[gcol];
                if (RELU) v = fmaxf(v, 0.0f);
                if (OUTF32)
                    ((float*)Cv)[(size_t)grow * ldc + gcol] = v;
                else
                    ((bf16*)Cv)[(size_t)grow * ldc + gcol] = __float2bfloat16(v);
            }
        }
    }
}

// ---------------------------------------------------------------------------
// Attention v4.2: v4.1 structure (zero main-loop barriers, K resident,
// V transposed in LDS, in-register softmax, per-wave PV transpose chunk)
// with (a) balanced tile map — per-wave variable QK/PV cost max 35 -> 32
// units — and (b) s_setprio(1) around QK/PV MFMA clusters (m191: +4-7% on
// independent-wave attn). LDS = 104 KB.
#define KS_LD  72
#define VT_LD  354

__device__ __forceinline__ int tile_of(int w, int it)
{
    // coverage: it0 -> 13..20, it1 -> 5..12, it2 -> 0..4 (waves 3..7)
    // per-wave variable cost (tile+1 sums): {27,27,27,29,30,31,32,28}
    const int m[3][8] = {
        {20, 19, 18, 17, 16, 15, 14, 13},
        { 5,  6,  7,  8,  9, 10, 11, 12},
        {-1, -1, -1,  1,  2,  3,  4,  0},
    };
    return m[it][w];
}

__global__ __launch_bounds__(512) void attn_kernel(
    bf16* __restrict__ qkv, float* __restrict__ attn_out)
{
    __shared__ alignas(16) bf16 Ks[336 * KS_LD];        // 48384 B
    __shared__ alignas(16) bf16 Vt[64 * VT_LD + 32];    // 45376 B
    __shared__ alignas(16) bf16 ptile[8][16 * 40];      // 10240 B
    const int t = threadIdx.x, lane = t & 63, w = t >> 6;
    const int h = blockIdx.x & 7, bt = blockIdx.x >> 3;
    const size_t rowbase = (size_t)bt * N_TOK;
    const int lrow = lane & 15, lk8 = (lane >> 4) * 8;
    const int r4 = (lane >> 4) * 4;
    const int b = bt / 12, tt2 = bt % 12;
    const size_t hb_base = (((size_t)(h * 8 + b)) * 12 + tt2) * N_TOK;

    for (int task = t; task < 336 * 8; task += 512) {
        int m = task >> 3, e0 = (task & 7) << 3;
        short8 v = {0, 0, 0, 0, 0, 0, 0, 0};
        if (m < N_TOK)
            v = *(const short8*)(qkv + (rowbase + m) * QKV_LD + 512 + h * 64 + e0);
        *(short8*)&Ks[m * KS_LD + e0] = v;
    }
    for (int task = t; task < 352 * 8; task += 512) {
        int m = task >> 3, e0 = (task & 7) << 3;
        short8 v = {0, 0, 0, 0, 0, 0, 0, 0};
        if (m < N_TOK)
            v = *(const short8*)(qkv + (rowbase + m) * QKV_LD + 1024 + h * 64 + e0);
#pragma unroll
        for (int j = 0; j < 8; ++j)
            Vt[(e0 + j) * VT_LD + m] = ((bf16*)&v)[j];
    }
    __syncthreads();   // the only block-wide barrier

    for (int it = 0; it < 3; ++it) {
        const int tile = tile_of(w, it);      // wave-uniform
        if (tile < 0) continue;
        const int r0 = tile * 16;

        int qrow = r0 + lrow; if (qrow > N_TOK - 1) qrow = N_TOK - 1;
        const bf16* qp = qkv + (rowbase + qrow) * QKV_LD + h * 64 + lk8;
        short8 qa0 = *(const short8*)(qp);
        short8 qa1 = *(const short8*)(qp + 32);

        f32x4 f[22];
        f[21] = (f32x4){0.f, 0.f, 0.f, 0.f};
#pragma unroll
        for (int ct = 0; ct < 21; ++ct) {
            if (ct <= tile) {                 // wave-uniform branch
                f32x4 a = {0.f, 0.f, 0.f, 0.f};
                short8 kb0 = *(const short8*)&Ks[(ct * 16 + lrow) * KS_LD + lk8];
                short8 kb1 = *(const short8*)&Ks[(ct * 16 + lrow) * KS_LD + 32 + lk8];
                __builtin_amdgcn_s_setprio(1);
                a = __builtin_amdgcn_mfma_f32_16x16x32_bf16(qa0, kb0, a, 0, 0, 0);
                a = __builtin_amdgcn_mfma_f32_16x16x32_bf16(qa1, kb1, a, 0, 0, 0);
                __builtin_amdgcn_s_setprio(0);
                f[ct] = a;
            }
        }

        float mx[4] = {-1e30f, -1e30f, -1e30f, -1e30f};
        float sm[4] = {0.f, 0.f, 0.f, 0.f};
#pragma unroll
        for (int ct = 0; ct < 21; ++ct) {
            if (ct <= tile) {
                const int c = ct * 16 + lrow;
#pragma unroll
                for (int r = 0; r < 4; ++r)
                    if (c <= r0 + r4 + r) mx[r] = fmaxf(mx[r], f[ct][r]);
            }
        }
#pragma unroll
        for (int r = 0; r < 4; ++r) {
#pragma unroll
            for (int o = 1; o < 16; o <<= 1) mx[r] = fmaxf(mx[r], __shfl_xor(mx[r], o));
        }
#pragma unroll
        for (int ct = 0; ct < 21; ++ct) {
            if (ct <= tile) {
                const int c = ct * 16 + lrow;
#pragma unroll
                for (int r = 0; r < 4; ++r) {
                    float e = (c <= r0 + r4 + r)
                                  ? __expf((f[ct][r] - mx[r]) * 0.125f) : 0.f;
                    f[ct][r] = e;
                    sm[r] += e;
                }
            }
        }
#pragma unroll
        for (int r = 0; r < 4; ++r) {
#pragma unroll
            for (int o = 1; o < 16; o <<= 1) sm[r] += __shfl_xor(sm[r], o);
            sm[r] = 1.0f / sm[r];
        }
#pragma unroll
        for (int ct = 0; ct < 21; ++ct) {
            if (ct <= tile) {
#pragma unroll
                for (int r = 0; r < 4; ++r) f[ct][r] *= sm[r];
            }
        }

#pragma unroll
        for (int ct = 0; ct < 21; ++ct) {
            const int c = ct * 16 + lrow;
            if (c < N_TOK) {
#pragma unroll
                for (int r = 0; r < 4; ++r) {
                    const int n = r0 + r4 + r;
                    if (n < N_TOK) {
                        float v = (ct <= tile && c <= n) ? f[ct][r] : 0.f;
                        attn_out[(hb_base + n) * N_TOK + c] = v;
                    }
                }
            }
        }

        f32x4 acc[4] = {};
        bf16* pt = &ptile[w][0];
#pragma unroll
        for (int s = 0; s < 11; ++s) {
            if (s <= (tile >> 1)) {           // wave-uniform
#pragma unroll
                for (int half = 0; half < 2; ++half) {
                    const int ct2 = 2 * s + half;
                    const int c = ct2 * 16 + lrow;
#pragma unroll
                    for (int r = 0; r < 4; ++r) {
                        const int n = r0 + r4 + r;
                        float v = (ct2 <= tile && c <= n) ? f[ct2][r] : 0.f;
                        pt[(r4 + r) * 40 + half * 16 + lrow] = __float2bfloat16(v);
                    }
                }
                short8 aa = *(const short8*)&pt[lrow * 40 + lk8];
                __builtin_amdgcn_s_setprio(1);
#pragma unroll
                for (int e = 0; e < 4; ++e) {
                    short8 bb = *(const short8*)&Vt[(e * 16 + lrow) * VT_LD + s * 32 + lk8];
                    acc[e] = __builtin_amdgcn_mfma_f32_16x16x32_bf16(aa, bb, acc[e], 0, 0, 0);
                }
                __builtin_amdgcn_s_setprio(0);
            }
        }

#pragma unroll
        for (int e = 0; e < 4; ++e) {
#pragma unroll
            for (int r = 0; r < 4; ++r) {
                const int n = r0 + r4 + r;
                if (n < N_TOK)
                    qkv[(rowbase + n) * QKV_LD + h * 64 + e * 16 + lrow] =
                        __float2bfloat16(acc[e][r]);
            }
        }
    }
}

// ---------------------------------------------------------------------------
extern "C" void kernel_launch(void* const* d_in, const int* in_sizes, int n_in,
                              void* d_out, int out_size, void* d_ws, size_t ws_size,
                              hipStream_t stream)
{
    const void* X   = d_in[0];
    const void* STE = d_in[1];
    const void* Wq  = d_in[2];
    const void* bq  = d_in[3];
    const void* Wk  = d_in[4];
    const void* bk  = d_in[5];
    const void* Wv  = d_in[6];
    const void* bv  = d_in[7];
    const void* W1  = d_in[8];
    const void* b1  = d_in[9];
    const void* W2  = d_in[10];
    const void* b2  = d_in[11];

    float* out0     = (float*)d_out;                              // [31200][512] f32
    float* attn_out = (float*)d_out + (size_t)M_ROWS * D_MODEL;   // [64][12][325][325] f32
    bf16*  Xc       = (bf16*)attn_out;   // scratch; overwritten by attn_kernel later

    char* ws = (char*)d_ws;
    bf16*  qkv   = (bf16*)(ws);                      // 31232*1536*2 = 95,944,704
    bf16*  BtQKV = (bf16*)(ws + 95944704);           //  3,145,728
    bf16*  W1T   = (bf16*)(ws + 99090432);           //    524,288
    bf16*  W2T   = (bf16*)(ws + 99614720);           //    524,288
    float* biasQ = (float*)(ws + 100139008);         //      6,144
    float* b1f   = (float*)(ws + 100145152);         //      2,048
    float* b2f   = (float*)(ws + 100147200);         //      2,048
    int*   flag  = (int*)(ws + 100149248);           //          4
    bf16*  hbuf  = qkv + 512;                        // FFN hidden aliases k-slice

    init_flag<<<1, 64, 0, stream>>>(flag);
    detect_dtype<<<64, 256, 0, stream>>>((const unsigned short*)X, flag);

    // all 5 weight transposes in one launch
    transpose_w_all<<<2048, 256, 0, stream>>>(Wq, Wk, Wv, W1, W2,
                                              BtQKV, W1T, W2T, flag);
    prep_bias<<<2, 256, 0, stream>>>(bq, bk, bv, b1, b2, biasQ, b1f, b2f, flag);

    // concat(X,STE) -> bf16 Xc [31232][1024]
    concat_cast<<<(M_PAD * 128) / 256, 256, 0, stream>>>(X, STE, Xc, flag);

    // QKV projection: Xc[31232,1024] @ BtQKV^T -> qkv (+bias, relu)
    gemm_lds256<0, 1><<<122 * 12, 512, 0, stream>>>(
        Xc, 1024, BtQKV, 1024, biasQ, qkv, M_PAD, 1024, QKV_LD, 12);

    // attention (ctx -> q-slice of qkv; attn -> f32 d_out region, overwrites Xc)
    attn_kernel<<<768, 512, 0, stream>>>(qkv, attn_out);

    // FFN1: relu(ctx @ W1 + b1) -> hbuf (k-slice of qkv)
    gemm_lds256<0, 1><<<122 * 4, 512, 0, stream>>>(
        qkv, QKV_LD, W1T, 512, b1f, hbuf, M_PAD, 512, QKV_LD, 4);

    // FFN2: hbuf @ W2 + b2 -> out0 (f32, guarded at M_ROWS)
    gemm_lds256<1, 0><<<122 * 4, 512, 0, stream>>>(
        hbuf, QKV_LD, W2T, 512, b2f, out0, M_ROWS, 512, D_MODEL, 4);
}